// Round 3
// baseline (147.183 us; speedup 1.0000x reference)
//
#include <hip/hip_runtime.h>

// focal_loss scalar reduction:
//   out = COEF * sum_i [ idx==0 ? log(p_i) : idx==1 ? log1p(-p_i) : 0 ]
//
// R2 post-mortem: compiler defeated the x4 unroll (VGPR=28 -> loads issued
// pairwise with vmcnt(0) between; ~2KB/wave in flight -> queueing-limited
// ~3 TB/s). R3: force MLP by construction — fixed 8 quads/thread, all 16
// dwordx4 loads issued into distinct registers before ANY use. VGPR ~80,
// launch_bounds(256,4) -> 16 waves/CU, 256 KB/CU outstanding demand.

static constexpr int BLOCK = 256;
static constexpr int GRID  = 2048;              // n4 = GRID*BLOCK*8 exactly
static constexpr int PT    = 8;                 // float4-quads per thread
static constexpr float COEF = 0.004f;           // WF * (1-0.8)^2
static constexpr float LN2  = 0.69314718055994530942f;

__device__ __forceinline__ float sel_log2(float pv, int iv) {
    return __log2f((iv == 0) ? pv : 1.0f - pv);
}

__global__ __launch_bounds__(BLOCK, 4) void fl_partial(
    const float* __restrict__ p,
    const int*   __restrict__ idx,
    float*       __restrict__ partials,
    int n)
{
    const float4* __restrict__ p4 = reinterpret_cast<const float4*>(p);
    const int4*   __restrict__ i4 = reinterpret_cast<const int4*>(idx);
    const int n4 = n >> 2;
    const int stride = GRID * BLOCK;
    const int base = blockIdx.x * BLOCK + threadIdx.x;

    float acc = 0.0f;

    if (n4 == GRID * BLOCK * PT) {
        // Fast path: all 16 loads in flight before any consumption.
        float4 pv[PT];
        int4   iv[PT];
#pragma unroll
        for (int k = 0; k < PT; ++k) pv[k] = p4[base + k * stride];
#pragma unroll
        for (int k = 0; k < PT; ++k) iv[k] = i4[base + k * stride];
#pragma unroll
        for (int k = 0; k < PT; ++k) {
            acc += sel_log2(pv[k].x, iv[k].x);
            acc += sel_log2(pv[k].y, iv[k].y);
            acc += sel_log2(pv[k].z, iv[k].z);
            acc += sel_log2(pv[k].w, iv[k].w);
        }
    } else {
        // Generic fallback (unused for this problem's fixed N).
        for (int i = base; i < n4; i += stride) {
            float4 pv = p4[i];
            int4   iv = i4[i];
            acc += sel_log2(pv.x, iv.x); acc += sel_log2(pv.y, iv.y);
            acc += sel_log2(pv.z, iv.z); acc += sel_log2(pv.w, iv.w);
        }
        if (base == 0)
            for (int j = n4 << 2; j < n; ++j)
                acc += sel_log2(p[j], idx[j]);
    }

    // wave-64 butterfly reduce
    for (int off = 32; off > 0; off >>= 1)
        acc += __shfl_down(acc, off, 64);

    __shared__ float ws[BLOCK / 64];
    const int lane = threadIdx.x & 63;
    const int wave = threadIdx.x >> 6;
    if (lane == 0) ws[wave] = acc;
    __syncthreads();
    if (threadIdx.x == 0)
        partials[blockIdx.x] = ws[0] + ws[1] + ws[2] + ws[3];
}

__global__ __launch_bounds__(BLOCK) void fl_final(
    const float* __restrict__ partials,
    float*       __restrict__ out)
{
    float acc = 0.0f;
    for (int i = threadIdx.x; i < GRID; i += BLOCK)
        acc += partials[i];
    for (int off = 32; off > 0; off >>= 1)
        acc += __shfl_down(acc, off, 64);

    __shared__ float ws[BLOCK / 64];
    const int lane = threadIdx.x & 63;
    const int wave = threadIdx.x >> 6;
    if (lane == 0) ws[wave] = acc;
    __syncthreads();
    if (threadIdx.x == 0)
        out[0] = (ws[0] + ws[1] + ws[2] + ws[3]) * (COEF * LN2);
}

extern "C" void kernel_launch(void* const* d_in, const int* in_sizes, int n_in,
                              void* d_out, int out_size, void* d_ws, size_t ws_size,
                              hipStream_t stream)
{
    const float* p   = (const float*)d_in[0];
    const int*   idx = (const int*)d_in[1];
    float* partials  = (float*)d_ws;      // GRID floats = 8 KB scratch
    const int n = in_sizes[0];

    fl_partial<<<GRID, BLOCK, 0, stream>>>(p, idx, partials, n);
    fl_final<<<1, BLOCK, 0, stream>>>(partials, (float*)d_out);
}

// Round 5
// 140.352 us; speedup vs baseline: 1.0487x; 1.0487x over previous
//
#include <hip/hip_runtime.h>

// focal_loss scalar reduction:
//   out = COEF * sum_i [ idx==0 ? log(p_i) : idx==1 ? log1p(-p_i) : 0 ]
//
// R1-R3: three code shapes (VGPR 12/28/36, occ 40-65%) all pin at ~3.0 TB/s
// read delivery, HBM-cold AND L3-warm -> delivery-rate cap, not MLP.
// R4 (this round, compile-fixed): test nontemporal/streaming fill policy so
// the 134MB stream stops thrashing the 32MB L2. Uses clang ext_vector_type
// (HIP_vector_type structs are rejected by __builtin_nontemporal_load).
// If neutral, ~44 us IS the read-path roofline for this pattern.

static constexpr int BLOCK = 256;
static constexpr int GRID  = 4096;              // 4 quads/thread
static constexpr float COEF = 0.004f;           // WF * (1-0.8)^2
static constexpr float LN2  = 0.69314718055994530942f;

typedef float fvec4 __attribute__((ext_vector_type(4)));
typedef int   ivec4 __attribute__((ext_vector_type(4)));

__device__ __forceinline__ float sel_log2(float pv, int iv) {
    return __log2f((iv == 0) ? pv : 1.0f - pv);
}

__global__ __launch_bounds__(BLOCK) void fl_partial(
    const float* __restrict__ p,
    const int*   __restrict__ idx,
    float*       __restrict__ partials,
    int n)
{
    const fvec4* __restrict__ p4 = reinterpret_cast<const fvec4*>(p);
    const ivec4* __restrict__ i4 = reinterpret_cast<const ivec4*>(idx);
    const int n4 = n >> 2;
    const int stride = GRID * BLOCK;
    int i = blockIdx.x * BLOCK + threadIdx.x;

    float acc = 0.0f;
    for (; i < n4; i += stride) {
        fvec4 pv = __builtin_nontemporal_load(&p4[i]);
        ivec4 iv = __builtin_nontemporal_load(&i4[i]);
        acc += sel_log2(pv.x, iv.x);
        acc += sel_log2(pv.y, iv.y);
        acc += sel_log2(pv.z, iv.z);
        acc += sel_log2(pv.w, iv.w);
    }
    // scalar tail (n % 4)
    if (blockIdx.x == 0 && threadIdx.x == 0) {
        for (int j = n4 << 2; j < n; ++j)
            acc += sel_log2(p[j], idx[j]);
    }

    // wave-64 butterfly reduce
    for (int off = 32; off > 0; off >>= 1)
        acc += __shfl_down(acc, off, 64);

    __shared__ float ws[BLOCK / 64];
    const int lane = threadIdx.x & 63;
    const int wave = threadIdx.x >> 6;
    if (lane == 0) ws[wave] = acc;
    __syncthreads();
    if (threadIdx.x == 0)
        partials[blockIdx.x] = ws[0] + ws[1] + ws[2] + ws[3];
}

__global__ __launch_bounds__(BLOCK) void fl_final(
    const float* __restrict__ partials,
    float*       __restrict__ out)
{
    float acc = 0.0f;
    for (int i = threadIdx.x; i < GRID; i += BLOCK)
        acc += partials[i];
    for (int off = 32; off > 0; off >>= 1)
        acc += __shfl_down(acc, off, 64);

    __shared__ float ws[BLOCK / 64];
    const int lane = threadIdx.x & 63;
    const int wave = threadIdx.x >> 6;
    if (lane == 0) ws[wave] = acc;
    __syncthreads();
    if (threadIdx.x == 0)
        out[0] = (ws[0] + ws[1] + ws[2] + ws[3]) * (COEF * LN2);
}

extern "C" void kernel_launch(void* const* d_in, const int* in_sizes, int n_in,
                              void* d_out, int out_size, void* d_ws, size_t ws_size,
                              hipStream_t stream)
{
    const float* p   = (const float*)d_in[0];
    const int*   idx = (const int*)d_in[1];
    float* partials  = (float*)d_ws;      // GRID floats = 16 KB scratch
    const int n = in_sizes[0];

    fl_partial<<<GRID, BLOCK, 0, stream>>>(p, idx, partials, n);
    fl_final<<<1, BLOCK, 0, stream>>>(partials, (float*)d_out);
}